// Round 1
// baseline (6289.050 us; speedup 1.0000x reference)
//
#include <hip/hip_runtime.h>

#define B_ 8192
#define D_ 1024
#define K_ 4096
#define H_ 8

#define BM 128
#define BN 128
#define BKD 16
#define KB (K_ / BN)   // 32 k-blocks per row

__device__ __forceinline__ void amin(float& v, int& i, float v2, int i2) {
    // lower value wins; on exact tie, lower index wins (== NumPy first-occurrence)
    if (v2 < v || (v2 == v && i2 < i)) { v = v2; i = i2; }
}

// ---------------------------------------------------------------------------
// ee[h*K + k] = sum_d codebooks[h][k][d]^2   (one block per codeword)
// ---------------------------------------------------------------------------
__global__ __launch_bounds__(256) void ee_kernel(const float* __restrict__ cb,
                                                 float* __restrict__ ee) {
    const int row = blockIdx.x;                 // 0 .. H*K-1
    const float4* p = reinterpret_cast<const float4*>(cb + (size_t)row * D_);
    const int t = threadIdx.x;
    float4 v = p[t];
    float s = v.x * v.x + v.y * v.y + v.z * v.z + v.w * v.w;
    #pragma unroll
    for (int m = 1; m < 64; m <<= 1) s += __shfl_xor(s, m);
    __shared__ float ls[4];
    if ((t & 63) == 0) ls[t >> 6] = s;
    __syncthreads();
    if (t == 0) ee[row] = (ls[0] + ls[1]) + (ls[2] + ls[3]);
}

// ---------------------------------------------------------------------------
// resid = x ; rr[b] = ||x_b||^2   (one block per row)
// ---------------------------------------------------------------------------
__global__ __launch_bounds__(256) void init_kernel(const float* __restrict__ x,
                                                   float* __restrict__ resid,
                                                   float* __restrict__ rr) {
    const int b = blockIdx.x;
    const int t = threadIdx.x;
    const float4* px = reinterpret_cast<const float4*>(x + (size_t)b * D_);
    float4* pr = reinterpret_cast<float4*>(resid + (size_t)b * D_);
    float4 v = px[t];
    pr[t] = v;
    float s = v.x * v.x + v.y * v.y + v.z * v.z + v.w * v.w;
    #pragma unroll
    for (int m = 1; m < 64; m <<= 1) s += __shfl_xor(s, m);
    __shared__ float ls[4];
    if ((t & 63) == 0) ls[t >> 6] = s;
    __syncthreads();
    if (t == 0) rr[b] = (ls[0] + ls[1]) + (ls[2] + ls[3]);
}

// ---------------------------------------------------------------------------
// Fused GEMM + partial argmin.
//   dist[b][k] = (rr[b] - 2*dot(resid_b, E_k)) + ee[k]
// Each block: BM=128 rows x BN=128 cols, 256 threads, 8x8 per-thread tile
// (split 4+4 so float4 LDS reads are <=2-way bank-aliased = free).
// Writes per-(row, k-block) argmin partials.
// ---------------------------------------------------------------------------
__global__ __launch_bounds__(256) void score_kernel(
    const float* __restrict__ A,    // resid [B][D]
    const float* __restrict__ Bm,   // E     [K][D]   (head slice)
    const float* __restrict__ ee,   // [K]            (head slice)
    const float* __restrict__ rr,   // [B]
    float* __restrict__ pval,       // [B][KB]
    int* __restrict__ pidx) {       // [B][KB]
    __shared__ float As[BKD][BM + 4];
    __shared__ float Bs[BKD][BN + 4];

    const int tid = threadIdx.x;
    const int tx = tid & 15;
    const int ty = tid >> 4;
    const int bm0 = blockIdx.y * BM;
    const int bn0 = blockIdx.x * BN;

    float acc[8][8];
    #pragma unroll
    for (int i = 0; i < 8; ++i)
        #pragma unroll
        for (int j = 0; j < 8; ++j) acc[i][j] = 0.f;

    const int srow = tid >> 2;          // 0..63
    const int sdq  = (tid & 3) * 4;     // d offset 0,4,8,12
    const float* A0 = A + (size_t)(bm0 + srow) * D_ + sdq;
    const float* A1 = A0 + (size_t)64 * D_;
    const float* B0 = Bm + (size_t)(bn0 + srow) * D_ + sdq;
    const float* B1 = B0 + (size_t)64 * D_;

    for (int d0 = 0; d0 < D_; d0 += BKD) {
        float4 a0 = *reinterpret_cast<const float4*>(A0 + d0);
        float4 a1 = *reinterpret_cast<const float4*>(A1 + d0);
        float4 b0 = *reinterpret_cast<const float4*>(B0 + d0);
        float4 b1 = *reinterpret_cast<const float4*>(B1 + d0);
        __syncthreads();   // previous iteration's reads complete
        As[sdq + 0][srow] = a0.x; As[sdq + 1][srow] = a0.y;
        As[sdq + 2][srow] = a0.z; As[sdq + 3][srow] = a0.w;
        As[sdq + 0][srow + 64] = a1.x; As[sdq + 1][srow + 64] = a1.y;
        As[sdq + 2][srow + 64] = a1.z; As[sdq + 3][srow + 64] = a1.w;
        Bs[sdq + 0][srow] = b0.x; Bs[sdq + 1][srow] = b0.y;
        Bs[sdq + 2][srow] = b0.z; Bs[sdq + 3][srow] = b0.w;
        Bs[sdq + 0][srow + 64] = b1.x; Bs[sdq + 1][srow + 64] = b1.y;
        Bs[sdq + 2][srow + 64] = b1.z; Bs[sdq + 3][srow + 64] = b1.w;
        __syncthreads();

        #pragma unroll
        for (int kk = 0; kk < BKD; ++kk) {
            float4 av0 = *reinterpret_cast<const float4*>(&As[kk][ty * 4]);
            float4 av1 = *reinterpret_cast<const float4*>(&As[kk][64 + ty * 4]);
            float4 bv0 = *reinterpret_cast<const float4*>(&Bs[kk][tx * 4]);
            float4 bv1 = *reinterpret_cast<const float4*>(&Bs[kk][64 + tx * 4]);
            float a[8] = {av0.x, av0.y, av0.z, av0.w, av1.x, av1.y, av1.z, av1.w};
            float b[8] = {bv0.x, bv0.y, bv0.z, bv0.w, bv1.x, bv1.y, bv1.z, bv1.w};
            #pragma unroll
            for (int i = 0; i < 8; ++i)
                #pragma unroll
                for (int j = 0; j < 8; ++j)
                    acc[i][j] = fmaf(a[i], b[j], acc[i][j]);
        }
    }

    // epilogue: score + per-row argmin across this block's 128 columns
    const float4* ee4 = reinterpret_cast<const float4*>(ee + bn0);
    float4 e0 = ee4[tx];
    float4 e1 = ee4[16 + tx];
    float eb[8] = {e0.x, e0.y, e0.z, e0.w, e1.x, e1.y, e1.z, e1.w};

    #pragma unroll
    for (int i = 0; i < 8; ++i) {
        const int rloc = (i < 4) ? (ty * 4 + i) : (64 + ty * 4 + (i - 4));
        const int r = bm0 + rloc;
        const float rv = rr[r];
        float bestv = 3.4e38f;
        int besti = 0x7fffffff;
        #pragma unroll
        for (int j = 0; j < 8; ++j) {
            const int c = bn0 + ((j < 4) ? (tx * 4 + j) : (64 + tx * 4 + (j - 4)));
            float t1 = 2.0f * acc[i][j];          // mimic reference op order
            float s = (rv - t1) + eb[j];
            amin(bestv, besti, s, c);
        }
        // reduce over the 16 tx lanes of this row group (within one wave)
        #pragma unroll
        for (int m = 1; m < 16; m <<= 1) {
            float ov = __shfl_xor(bestv, m);
            int oi = __shfl_xor(besti, m);
            amin(bestv, besti, ov, oi);
        }
        if (tx == 0) {
            pval[(size_t)r * KB + blockIdx.x] = bestv;
            pidx[(size_t)r * KB + blockIdx.x] = besti;
        }
    }
}

// ---------------------------------------------------------------------------
// Per row: final argmin over KB partials, gather E[idx], update resid /
// quantized exactly as the reference (elementwise fp32), emit code + new rr.
// ---------------------------------------------------------------------------
__global__ __launch_bounds__(256) void update_kernel(
    float* __restrict__ resid,
    const float* __restrict__ E,       // head codebook [K][D]
    const float* __restrict__ pval,
    const int* __restrict__ pidx,
    float* __restrict__ rr,
    float* __restrict__ quant,         // d_out
    float* __restrict__ codes,         // d_out + B*D
    int h) {
    const int b = blockIdx.x;
    const int t = threadIdx.x;
    __shared__ int sidx;
    __shared__ float ls[4];

    if (t < 64) {
        float v = 3.4e38f;
        int i = 0x7fffffff;
        if (t < KB) { v = pval[(size_t)b * KB + t]; i = pidx[(size_t)b * KB + t]; }
        #pragma unroll
        for (int m = 1; m < 32; m <<= 1) {
            float ov = __shfl_xor(v, m);
            int oi = __shfl_xor(i, m);
            amin(v, i, ov, oi);
        }
        if (t == 0) {
            sidx = i;
            codes[(size_t)b * H_ + h] = (float)i;
        }
    }
    __syncthreads();
    const int idx = sidx;

    const float4* q4 = reinterpret_cast<const float4*>(E + (size_t)idx * D_);
    float4* r4 = reinterpret_cast<float4*>(resid + (size_t)b * D_);
    float4* o4 = reinterpret_cast<float4*>(quant + (size_t)b * D_);

    float4 q = q4[t];
    float4 r = r4[t];
    r.x -= q.x; r.y -= q.y; r.z -= q.z; r.w -= q.w;
    r4[t] = r;

    float4 o;
    if (h == 0) {
        o = q;
    } else {
        o = o4[t];
        o.x += q.x; o.y += q.y; o.z += q.z; o.w += q.w;
    }
    o4[t] = o;

    float s = r.x * r.x + r.y * r.y + r.z * r.z + r.w * r.w;
    #pragma unroll
    for (int m = 1; m < 64; m <<= 1) s += __shfl_xor(s, m);
    if ((t & 63) == 0) ls[t >> 6] = s;
    __syncthreads();
    if (t == 0) rr[b] = (ls[0] + ls[1]) + (ls[2] + ls[3]);
}

// ---------------------------------------------------------------------------
extern "C" void kernel_launch(void* const* d_in, const int* in_sizes, int n_in,
                              void* d_out, int out_size, void* d_ws, size_t ws_size,
                              hipStream_t stream) {
    const float* x  = (const float*)d_in[0];   // [B][1][D]
    const float* cb = (const float*)d_in[1];   // [H][K][D]
    float* out = (float*)d_out;
    float* quant = out;                         // [B][D]
    float* codes = out + (size_t)B_ * D_;       // [B][H] (as floats)

    char* ws = (char*)d_ws;
    float* resid = (float*)ws;                                   // 32 MiB
    float* rr    = (float*)(ws + (size_t)B_ * D_ * 4);           // 32 KiB
    float* ee    = (float*)(ws + (size_t)B_ * D_ * 4 + B_ * 4);  // 128 KiB
    float* pval  = (float*)(ws + (size_t)B_ * D_ * 4 + B_ * 4 + (size_t)H_ * K_ * 4);
    int*   pidx  = (int*)  (ws + (size_t)B_ * D_ * 4 + B_ * 4 + (size_t)H_ * K_ * 4
                               + (size_t)B_ * KB * 4);

    hipLaunchKernelGGL(ee_kernel, dim3(H_ * K_), dim3(256), 0, stream, cb, ee);
    hipLaunchKernelGGL(init_kernel, dim3(B_), dim3(256), 0, stream, x, resid, rr);

    for (int h = 0; h < H_; ++h) {
        const float* E  = cb + (size_t)h * K_ * D_;
        const float* eh = ee + (size_t)h * K_;
        hipLaunchKernelGGL(score_kernel, dim3(KB, B_ / BM), dim3(256), 0, stream,
                           resid, E, eh, rr, pval, pidx);
        hipLaunchKernelGGL(update_kernel, dim3(B_), dim3(256), 0, stream,
                           resid, E, pval, pidx, rr, quant, codes, h);
    }
}

// Round 5
// 2703.457 us; speedup vs baseline: 2.3263x; 2.3263x over previous
//
#include <hip/hip_runtime.h>

#define B_ 8192
#define D_ 1024
#define K_ 4096
#define H_ 8

#define BM 128
#define BN 128
#define BK 32
#define NBLK 64        // 64-col argmin blocks per row: (K_/BN)*2 wave-cols
#define NCAND 8        // exact-rescored candidates per row

typedef __attribute__((ext_vector_type(8))) short short8v;
typedef __attribute__((ext_vector_type(4))) float f32x4;

#define FINF 3.4e38f
#define IBIG 0x7fffffff

__device__ __forceinline__ void amin(float& v, int& i, float v2, int i2) {
    if (v2 < v || (v2 == v && i2 < i)) { v = v2; i = i2; }
}

__device__ __forceinline__ unsigned short f2bf_rn(float x) {
    unsigned int u = __float_as_uint(x);
    unsigned int r = (u + 0x7fffu + ((u >> 16) & 1u)) >> 16;
    return (unsigned short)r;
}
__device__ __forceinline__ float bf2f(unsigned short h) {
    return __uint_as_float(((unsigned int)h) << 16);
}
__device__ __forceinline__ void bsplit(float x, unsigned short& h, unsigned short& l) {
    h = f2bf_rn(x);
    l = f2bf_rn(x - bf2f(h));
}

__device__ __forceinline__ void gload16(const unsigned short* g, unsigned short* l) {
    __builtin_amdgcn_global_load_lds(
        (const __attribute__((address_space(1))) void*)g,
        (__attribute__((address_space(3))) void*)l, 16, 0, 0);
}

// ---------------------------------------------------------------------------
// ee[h*K + k] = sum_d cb[h][k][d]^2
// ---------------------------------------------------------------------------
__global__ __launch_bounds__(256) void ee_kernel(const float* __restrict__ cb,
                                                 float* __restrict__ ee) {
    const int row = blockIdx.x;
    const float4* p = reinterpret_cast<const float4*>(cb + (size_t)row * D_);
    const int t = threadIdx.x;
    float4 v = p[t];
    float s = v.x * v.x + v.y * v.y + v.z * v.z + v.w * v.w;
    #pragma unroll
    for (int m = 1; m < 64; m <<= 1) s += __shfl_xor(s, m);
    __shared__ float ls[4];
    if ((t & 63) == 0) ls[t >> 6] = s;
    __syncthreads();
    if (t == 0) ee[row] = (ls[0] + ls[1]) + (ls[2] + ls[3]);
}

// ---------------------------------------------------------------------------
// codebook head -> bf16 hi/lo split
// ---------------------------------------------------------------------------
__global__ __launch_bounds__(256) void cbconv_kernel(const float* __restrict__ cb,
                                                     unsigned short* __restrict__ hi,
                                                     unsigned short* __restrict__ lo) {
    const int row = blockIdx.x;
    const int t = threadIdx.x;
    float4 v = reinterpret_cast<const float4*>(cb + (size_t)row * D_)[t];
    ushort4 h, l;
    bsplit(v.x, h.x, l.x); bsplit(v.y, h.y, l.y);
    bsplit(v.z, h.z, l.z); bsplit(v.w, h.w, l.w);
    reinterpret_cast<ushort4*>(hi + (size_t)row * D_)[t] = h;
    reinterpret_cast<ushort4*>(lo + (size_t)row * D_)[t] = l;
}

// ---------------------------------------------------------------------------
// resid = x ; rr = ||x||^2 ; resid hi/lo bf16 split
// ---------------------------------------------------------------------------
__global__ __launch_bounds__(256) void init_kernel(const float* __restrict__ x,
                                                   float* __restrict__ resid,
                                                   float* __restrict__ rr,
                                                   unsigned short* __restrict__ rhi,
                                                   unsigned short* __restrict__ rlo) {
    const int b = blockIdx.x;
    const int t = threadIdx.x;
    float4 v = reinterpret_cast<const float4*>(x + (size_t)b * D_)[t];
    reinterpret_cast<float4*>(resid + (size_t)b * D_)[t] = v;
    ushort4 h, l;
    bsplit(v.x, h.x, l.x); bsplit(v.y, h.y, l.y);
    bsplit(v.z, h.z, l.z); bsplit(v.w, h.w, l.w);
    reinterpret_cast<ushort4*>(rhi + (size_t)b * D_)[t] = h;
    reinterpret_cast<ushort4*>(rlo + (size_t)b * D_)[t] = l;
    float s = v.x * v.x + v.y * v.y + v.z * v.z + v.w * v.w;
    #pragma unroll
    for (int m = 1; m < 64; m <<= 1) s += __shfl_xor(s, m);
    __shared__ float ls[4];
    if ((t & 63) == 0) ls[t >> 6] = s;
    __syncthreads();
    if (t == 0) rr[b] = (ls[0] + ls[1]) + (ls[2] + ls[3]);
}

// ---------------------------------------------------------------------------
// MFMA split-bf16 approx score + fused per-(row, 64-col wave) TOP-2 argmin.
// dist[b][k] = (rr[b] - 2*dot(resid_b, E_k)) + ee[k]
// dot ~= hi*hi + hi*lo + lo*hi  (fp32 MFMA accumulator)
// ---------------------------------------------------------------------------
__global__ __launch_bounds__(256) void score_mfma_kernel(
    const unsigned short* __restrict__ Ah, const unsigned short* __restrict__ Al,
    const unsigned short* __restrict__ Bh, const unsigned short* __restrict__ Bl,
    const float* __restrict__ ee, const float* __restrict__ rr,
    float* __restrict__ pval, int* __restrict__ pidx) {
    __shared__ unsigned short lds[4][BM][BK];   // A_hi, A_lo, B_hi, B_lo : 32 KB

    const int tid = threadIdx.x;
    const int bn0 = blockIdx.x * BN;
    const int bm0 = blockIdx.y * BM;

    f32x4 acc[4][4];
    #pragma unroll
    for (int i = 0; i < 4; ++i)
        #pragma unroll
        for (int j = 0; j < 4; ++j)
            #pragma unroll
            for (int r = 0; r < 4; ++r) acc[i][j][r] = 0.f;

    const int srow = tid >> 2;
    const int sch  = (tid & 3) * 8;
    const size_t rstep = (size_t)64 * D_;
    const unsigned short* pAh = Ah + (size_t)(bm0 + srow) * D_ + sch;
    const unsigned short* pAl = Al + (size_t)(bm0 + srow) * D_ + sch;
    const unsigned short* pBh = Bh + (size_t)(bn0 + srow) * D_ + sch;
    const unsigned short* pBl = Bl + (size_t)(bn0 + srow) * D_ + sch;

    const int l  = tid & 63;
    const int w  = tid >> 6;
    const int wr = (w >> 1) * 64;
    const int wc = (w & 1) * 64;
    const int fr = l & 15;
    const int k8 = (l >> 4) * 8;

    for (int d0 = 0; d0 < D_; d0 += BK) {
        __syncthreads();
        gload16(pAh + d0,         &lds[0][srow][sch]);
        gload16(pAh + rstep + d0, &lds[0][srow + 64][sch]);
        gload16(pAl + d0,         &lds[1][srow][sch]);
        gload16(pAl + rstep + d0, &lds[1][srow + 64][sch]);
        gload16(pBh + d0,         &lds[2][srow][sch]);
        gload16(pBh + rstep + d0, &lds[2][srow + 64][sch]);
        gload16(pBl + d0,         &lds[3][srow][sch]);
        gload16(pBl + rstep + d0, &lds[3][srow + 64][sch]);
        __syncthreads();

        short8v a_h[4], a_l[4], b_h[4], b_l[4];
        #pragma unroll
        for (int f = 0; f < 4; ++f) {
            a_h[f] = *reinterpret_cast<const short8v*>(&lds[0][wr + f * 16 + fr][k8]);
            a_l[f] = *reinterpret_cast<const short8v*>(&lds[1][wr + f * 16 + fr][k8]);
            b_h[f] = *reinterpret_cast<const short8v*>(&lds[2][wc + f * 16 + fr][k8]);
            b_l[f] = *reinterpret_cast<const short8v*>(&lds[3][wc + f * 16 + fr][k8]);
        }
        #pragma unroll
        for (int i = 0; i < 4; ++i)
            #pragma unroll
            for (int j = 0; j < 4; ++j) {
                acc[i][j] = __builtin_amdgcn_mfma_f32_16x16x32_bf16(a_h[i], b_h[j], acc[i][j], 0, 0, 0);
                acc[i][j] = __builtin_amdgcn_mfma_f32_16x16x32_bf16(a_h[i], b_l[j], acc[i][j], 0, 0, 0);
                acc[i][j] = __builtin_amdgcn_mfma_f32_16x16x32_bf16(a_l[i], b_h[j], acc[i][j], 0, 0, 0);
            }
    }

    // epilogue: per-row TOP-2 over this wave's 64 columns
    // C/D layout: col = lane&15, row = (lane>>4)*4 + reg
    const int g4 = (l >> 4) * 4;
    float eb[4];
    #pragma unroll
    for (int j = 0; j < 4; ++j) eb[j] = ee[bn0 + wc + j * 16 + fr];
    const int blk = blockIdx.x * 2 + (w & 1);

    #pragma unroll
    for (int i = 0; i < 4; ++i) {
        #pragma unroll
        for (int r = 0; r < 4; ++r) {
            const int row = bm0 + wr + i * 16 + g4 + r;
            const float rv = rr[row];
            float sj[4]; int cj[4];
            float bv = FINF; int bi = IBIG;
            #pragma unroll
            for (int j = 0; j < 4; ++j) {
                cj[j] = bn0 + wc + j * 16 + fr;
                sj[j] = (rv - 2.0f * acc[i][j][r]) + eb[j];
                amin(bv, bi, sj[j], cj[j]);
            }
            #pragma unroll
            for (int m = 1; m < 16; m <<= 1) {
                float ov = __shfl_xor(bv, m);
                int oi = __shfl_xor(bi, m);
                amin(bv, bi, ov, oi);
            }
            // second best (exclude bi; all 16 lanes agree on bi)
            float bv2 = FINF; int bi2 = IBIG;
            #pragma unroll
            for (int j = 0; j < 4; ++j)
                if (cj[j] != bi) amin(bv2, bi2, sj[j], cj[j]);
            #pragma unroll
            for (int m = 1; m < 16; m <<= 1) {
                float ov = __shfl_xor(bv2, m);
                int oi = __shfl_xor(bi2, m);
                amin(bv2, bi2, ov, oi);
            }
            if (fr == 0) {
                const size_t base = ((size_t)row * NBLK + blk) * 2;
                pval[base] = bv;  pidx[base] = bi;
                pval[base + 1] = bv2; pidx[base + 1] = bi2;
            }
        }
    }
}

// ---------------------------------------------------------------------------
// Per row: top-NCAND candidate extraction from 128 partials, EXACT fp32
// rescore of candidates, argmin, then exact resid/quant update + re-split.
// ---------------------------------------------------------------------------
__global__ __launch_bounds__(256) void update_kernel(
    float* __restrict__ resid,
    const float* __restrict__ E,
    const float* __restrict__ ee,
    const float* __restrict__ pval,
    const int* __restrict__ pidx,
    float* __restrict__ rr,
    float* __restrict__ quant,
    float* __restrict__ codes,
    unsigned short* __restrict__ rhi,
    unsigned short* __restrict__ rlo,
    int h) {
    const int b = blockIdx.x;
    const int t = threadIdx.x;
    __shared__ int scand[NCAND];
    __shared__ float sdot[NCAND];
    __shared__ int ssel;
    __shared__ float ls[4];

    // --- candidate extraction: wave 0, lane t owns partial pair for block t
    if (t < 64) {
        const size_t base = ((size_t)b * NBLK + t) * 2;
        float v0 = pval[base], v1 = pval[base + 1];
        int i0 = pidx[base], i1 = pidx[base + 1];
        #pragma unroll
        for (int r = 0; r < NCAND; ++r) {
            float av = v0; int ai = i0;
            amin(av, ai, v1, i1);
            #pragma unroll
            for (int m = 1; m < 64; m <<= 1) {
                float ov = __shfl_xor(av, m);
                int oi = __shfl_xor(ai, m);
                amin(av, ai, ov, oi);
            }
            if (ai == i0) v0 = FINF;   // consume (indices unique across partials)
            if (ai == i1) v1 = FINF;
            if (t == 0) scand[r] = ai;
        }
    }
    __syncthreads();

    // --- exact fp32 rescore: wave w handles candidates w and w+4
    const int wv = t >> 6;
    const int l = t & 63;
    const float4* r4row = reinterpret_cast<const float4*>(resid + (size_t)b * D_);
    float4 rx[4];
    #pragma unroll
    for (int q = 0; q < 4; ++q) rx[q] = r4row[q * 64 + l];

    #pragma unroll
    for (int cpass = 0; cpass < 2; ++cpass) {
        const int c = wv + cpass * 4;
        const int idx = scand[c];
        const float4* e4 = reinterpret_cast<const float4*>(E + (size_t)idx * D_);
        float dot = 0.f;
        #pragma unroll
        for (int q = 0; q < 4; ++q) {
            float4 e = e4[q * 64 + l];
            dot = fmaf(rx[q].x, e.x, dot);
            dot = fmaf(rx[q].y, e.y, dot);
            dot = fmaf(rx[q].z, e.z, dot);
            dot = fmaf(rx[q].w, e.w, dot);
        }
        #pragma unroll
        for (int m = 1; m < 64; m <<= 1) dot += __shfl_xor(dot, m);
        if (l == 0) sdot[c] = dot;
    }
    __syncthreads();

    if (t == 0) {
        const float rv = rr[b];
        float bv = FINF; int bi = IBIG;
        #pragma unroll
        for (int c = 0; c < NCAND; ++c) {
            const int idx = scand[c];
            const float s = (rv - 2.0f * sdot[c]) + ee[idx];
            amin(bv, bi, s, idx);
        }
        ssel = bi;
        codes[(size_t)b * H_ + h] = (float)bi;
    }
    __syncthreads();
    const int idx = ssel;

    // --- exact fp32 update (order matches reference elementwise)
    const float4* q4 = reinterpret_cast<const float4*>(E + (size_t)idx * D_);
    float4* r4 = reinterpret_cast<float4*>(resid + (size_t)b * D_);
    float4* o4 = reinterpret_cast<float4*>(quant + (size_t)b * D_);

    float4 q = q4[t];
    float4 r = r4[t];
    r.x -= q.x; r.y -= q.y; r.z -= q.z; r.w -= q.w;
    r4[t] = r;

    ushort4 hh, llv;
    bsplit(r.x, hh.x, llv.x); bsplit(r.y, hh.y, llv.y);
    bsplit(r.z, hh.z, llv.z); bsplit(r.w, hh.w, llv.w);
    reinterpret_cast<ushort4*>(rhi + (size_t)b * D_)[t] = hh;
    reinterpret_cast<ushort4*>(rlo + (size_t)b * D_)[t] = llv;

    float4 o;
    if (h == 0) {
        o = q;
    } else {
        o = o4[t];
        o.x += q.x; o.y += q.y; o.z += q.z; o.w += q.w;
    }
    o4[t] = o;

    float s = r.x * r.x + r.y * r.y + r.z * r.z + r.w * r.w;
    #pragma unroll
    for (int m = 1; m < 64; m <<= 1) s += __shfl_xor(s, m);
    if ((t & 63) == 0) ls[t >> 6] = s;
    __syncthreads();
    if (t == 0) rr[b] = (ls[0] + ls[1]) + (ls[2] + ls[3]);
}

// ---------------------------------------------------------------------------
extern "C" void kernel_launch(void* const* d_in, const int* in_sizes, int n_in,
                              void* d_out, int out_size, void* d_ws, size_t ws_size,
                              hipStream_t stream) {
    const float* x  = (const float*)d_in[0];   // [B][1][D]
    const float* cb = (const float*)d_in[1];   // [H][K][D]
    float* out = (float*)d_out;
    float* quant = out;                          // [B][D]
    float* codes = out + (size_t)B_ * D_;        // [B][H] as float

    char* ws = (char*)d_ws;
    size_t off = 0;
    float* resid = (float*)(ws + off); off += (size_t)B_ * D_ * 4;          // 32 MB
    float* rr    = (float*)(ws + off); off += (size_t)B_ * 4;
    float* ee    = (float*)(ws + off); off += (size_t)H_ * K_ * 4;
    float* pval  = (float*)(ws + off); off += (size_t)B_ * NBLK * 2 * 4;    // 4 MB
    int*   pidx  = (int*)  (ws + off); off += (size_t)B_ * NBLK * 2 * 4;    // 4 MB
    unsigned short* rhi = (unsigned short*)(ws + off); off += (size_t)B_ * D_ * 2;  // 16 MB
    unsigned short* rlo = (unsigned short*)(ws + off); off += (size_t)B_ * D_ * 2;  // 16 MB
    unsigned short* chi = (unsigned short*)(ws + off); off += (size_t)K_ * D_ * 2;  // 8 MB
    unsigned short* clo = (unsigned short*)(ws + off); off += (size_t)K_ * D_ * 2;  // 8 MB

    hipLaunchKernelGGL(ee_kernel, dim3(H_ * K_), dim3(256), 0, stream, cb, ee);
    hipLaunchKernelGGL(init_kernel, dim3(B_), dim3(256), 0, stream, x, resid, rr, rhi, rlo);

    for (int h = 0; h < H_; ++h) {
        const float* E  = cb + (size_t)h * K_ * D_;
        const float* eh = ee + (size_t)h * K_;
        hipLaunchKernelGGL(cbconv_kernel, dim3(K_), dim3(256), 0, stream, E, chi, clo);
        hipLaunchKernelGGL(score_mfma_kernel, dim3(K_ / BN, B_ / BM), dim3(256), 0, stream,
                           rhi, rlo, chi, clo, eh, rr, pval, pidx);
        hipLaunchKernelGGL(update_kernel, dim3(B_), dim3(256), 0, stream,
                           resid, E, eh, pval, pidx, rr, quant, codes, rhi, rlo, h);
    }
}

// Round 6
// 1881.834 us; speedup vs baseline: 3.3420x; 1.4366x over previous
//
#include <hip/hip_runtime.h>

#define B_ 8192
#define D_ 1024
#define K_ 4096
#define H_ 8

#define BM 128
#define BN 128
#define BK 32
#define NBLK 64        // 64-col argmin blocks per row: (K_/BN)*2 wave-cols
#define TOPB 3         // candidates kept per 64-col block
#define NCAND 8        // exact-rescored candidates per row

typedef __attribute__((ext_vector_type(8))) short short8v;
typedef __attribute__((ext_vector_type(4))) float f32x4;

#define FINF 3.4e38f
#define IBIG 0x7fffffff

__device__ __forceinline__ void amin(float& v, int& i, float v2, int i2) {
    if (v2 < v || (v2 == v && i2 < i)) { v = v2; i = i2; }
}

__device__ __forceinline__ unsigned short f2bf_rn(float x) {
    unsigned int u = __float_as_uint(x);
    unsigned int r = (u + 0x7fffu + ((u >> 16) & 1u)) >> 16;
    return (unsigned short)r;
}

__device__ __forceinline__ void gload16(const unsigned short* g, unsigned short* l) {
    __builtin_amdgcn_global_load_lds(
        (const __attribute__((address_space(1))) void*)g,
        (__attribute__((address_space(3))) void*)l, 16, 0, 0);
}

// ---------------------------------------------------------------------------
// Per head: codebook row -> bf16 hi + ee[k] = ||E_k||^2 (fused single read)
// ---------------------------------------------------------------------------
__global__ __launch_bounds__(256) void cbconv_kernel(const float* __restrict__ E,
                                                     unsigned short* __restrict__ hi,
                                                     float* __restrict__ eeh) {
    const int row = blockIdx.x;
    const int t = threadIdx.x;
    float4 v = reinterpret_cast<const float4*>(E + (size_t)row * D_)[t];
    ushort4 h;
    h.x = f2bf_rn(v.x); h.y = f2bf_rn(v.y);
    h.z = f2bf_rn(v.z); h.w = f2bf_rn(v.w);
    reinterpret_cast<ushort4*>(hi + (size_t)row * D_)[t] = h;
    float s = v.x * v.x + v.y * v.y + v.z * v.z + v.w * v.w;
    #pragma unroll
    for (int m = 1; m < 64; m <<= 1) s += __shfl_xor(s, m);
    __shared__ float ls[4];
    if ((t & 63) == 0) ls[t >> 6] = s;
    __syncthreads();
    if (t == 0) eeh[row] = (ls[0] + ls[1]) + (ls[2] + ls[3]);
}

// ---------------------------------------------------------------------------
// resid = x ; rr = ||x||^2 ; resid bf16 hi
// ---------------------------------------------------------------------------
__global__ __launch_bounds__(256) void init_kernel(const float* __restrict__ x,
                                                   float* __restrict__ resid,
                                                   float* __restrict__ rr,
                                                   unsigned short* __restrict__ rhi) {
    const int b = blockIdx.x;
    const int t = threadIdx.x;
    float4 v = reinterpret_cast<const float4*>(x + (size_t)b * D_)[t];
    reinterpret_cast<float4*>(resid + (size_t)b * D_)[t] = v;
    ushort4 h;
    h.x = f2bf_rn(v.x); h.y = f2bf_rn(v.y);
    h.z = f2bf_rn(v.z); h.w = f2bf_rn(v.w);
    reinterpret_cast<ushort4*>(rhi + (size_t)b * D_)[t] = h;
    float s = v.x * v.x + v.y * v.y + v.z * v.z + v.w * v.w;
    #pragma unroll
    for (int m = 1; m < 64; m <<= 1) s += __shfl_xor(s, m);
    __shared__ float ls[4];
    if ((t & 63) == 0) ls[t >> 6] = s;
    __syncthreads();
    if (t == 0) rr[b] = (ls[0] + ls[1]) + (ls[2] + ls[3]);
}

// ---------------------------------------------------------------------------
// Single-pass bf16 MFMA approx score + fused per-(row, 64-col wave) TOP-3.
// dist[b][k] = (rr[b] - 2*dot(resid_b, E_k)) + ee[k] ; dot ~= hi*hi
// Approximation error is absorbed by the exact-rescore rescue in update.
// Block: 128x128 tile, 4 waves (2x2 of 64x64), BK=32, m97 2-barrier loop.
// ---------------------------------------------------------------------------
__global__ __launch_bounds__(256) void score_mfma_kernel(
    const unsigned short* __restrict__ Ah, const unsigned short* __restrict__ Bh,
    const float* __restrict__ ee, const float* __restrict__ rr,
    float* __restrict__ pval, int* __restrict__ pidx) {
    __shared__ unsigned short lds[2][BM][BK];   // A_hi, B_hi : 16 KB

    const int tid = threadIdx.x;
    const int bn0 = blockIdx.x * BN;
    const int bm0 = blockIdx.y * BM;

    f32x4 acc[4][4];
    #pragma unroll
    for (int i = 0; i < 4; ++i)
        #pragma unroll
        for (int j = 0; j < 4; ++j)
            #pragma unroll
            for (int r = 0; r < 4; ++r) acc[i][j][r] = 0.f;

    const int srow = tid >> 2;
    const int sch  = (tid & 3) * 8;
    const size_t rstep = (size_t)64 * D_;
    const unsigned short* pAh = Ah + (size_t)(bm0 + srow) * D_ + sch;
    const unsigned short* pBh = Bh + (size_t)(bn0 + srow) * D_ + sch;

    const int l  = tid & 63;
    const int w  = tid >> 6;
    const int wr = (w >> 1) * 64;
    const int wc = (w & 1) * 64;
    const int fr = l & 15;
    const int k8 = (l >> 4) * 8;

    for (int d0 = 0; d0 < D_; d0 += BK) {
        __syncthreads();
        gload16(pAh + d0,         &lds[0][srow][sch]);
        gload16(pAh + rstep + d0, &lds[0][srow + 64][sch]);
        gload16(pBh + d0,         &lds[1][srow][sch]);
        gload16(pBh + rstep + d0, &lds[1][srow + 64][sch]);
        __syncthreads();

        short8v a_h[4], b_h[4];
        #pragma unroll
        for (int f = 0; f < 4; ++f) {
            a_h[f] = *reinterpret_cast<const short8v*>(&lds[0][wr + f * 16 + fr][k8]);
            b_h[f] = *reinterpret_cast<const short8v*>(&lds[1][wc + f * 16 + fr][k8]);
        }
        #pragma unroll
        for (int i = 0; i < 4; ++i)
            #pragma unroll
            for (int j = 0; j < 4; ++j)
                acc[i][j] = __builtin_amdgcn_mfma_f32_16x16x32_bf16(a_h[i], b_h[j], acc[i][j], 0, 0, 0);
    }

    // epilogue: per-row TOP-3 over this wave's 64 columns
    // C/D layout: col = lane&15, row = (lane>>4)*4 + reg
    const int g4 = (l >> 4) * 4;
    float eb[4];
    #pragma unroll
    for (int j = 0; j < 4; ++j) eb[j] = ee[bn0 + wc + j * 16 + fr];
    const int blk = blockIdx.x * 2 + (w & 1);

    #pragma unroll
    for (int i = 0; i < 4; ++i) {
        #pragma unroll
        for (int r = 0; r < 4; ++r) {
            const int row = bm0 + wr + i * 16 + g4 + r;
            const float rv = rr[row];
            float sj[4]; int cj[4];
            float bv = FINF; int bi = IBIG;
            #pragma unroll
            for (int j = 0; j < 4; ++j) {
                cj[j] = bn0 + wc + j * 16 + fr;
                sj[j] = (rv - 2.0f * acc[i][j][r]) + eb[j];
                amin(bv, bi, sj[j], cj[j]);
            }
            #pragma unroll
            for (int m = 1; m < 16; m <<= 1) {
                float ov = __shfl_xor(bv, m);
                int oi = __shfl_xor(bi, m);
                amin(bv, bi, ov, oi);
            }
            float bv2 = FINF; int bi2 = IBIG;
            #pragma unroll
            for (int j = 0; j < 4; ++j)
                if (cj[j] != bi) amin(bv2, bi2, sj[j], cj[j]);
            #pragma unroll
            for (int m = 1; m < 16; m <<= 1) {
                float ov = __shfl_xor(bv2, m);
                int oi = __shfl_xor(bi2, m);
                amin(bv2, bi2, ov, oi);
            }
            float bv3 = FINF; int bi3 = IBIG;
            #pragma unroll
            for (int j = 0; j < 4; ++j)
                if (cj[j] != bi && cj[j] != bi2) amin(bv3, bi3, sj[j], cj[j]);
            #pragma unroll
            for (int m = 1; m < 16; m <<= 1) {
                float ov = __shfl_xor(bv3, m);
                int oi = __shfl_xor(bi3, m);
                amin(bv3, bi3, ov, oi);
            }
            if (fr == 0) {
                const size_t base = ((size_t)row * NBLK + blk) * TOPB;
                pval[base] = bv;      pidx[base] = bi;
                pval[base + 1] = bv2; pidx[base + 1] = bi2;
                pval[base + 2] = bv3; pidx[base + 2] = bi3;
            }
        }
    }
}

// ---------------------------------------------------------------------------
// Per row: top-NCAND candidate extraction from 192 partials, EXACT fp32
// rescore, argmin (value then lowest index), exact resid/quant update.
// ---------------------------------------------------------------------------
__global__ __launch_bounds__(256) void update_kernel(
    float* __restrict__ resid,
    const float* __restrict__ E,
    const float* __restrict__ ee,
    const float* __restrict__ pval,
    const int* __restrict__ pidx,
    float* __restrict__ rr,
    float* __restrict__ quant,
    float* __restrict__ codes,
    unsigned short* __restrict__ rhi,
    int h) {
    const int b = blockIdx.x;
    const int t = threadIdx.x;
    __shared__ int scand[NCAND];
    __shared__ float sdot[NCAND];
    __shared__ int ssel;
    __shared__ float ls[4];

    // --- candidate extraction: wave 0, lane t owns the 3 partials of block t
    if (t < 64) {
        const size_t base = ((size_t)b * NBLK + t) * TOPB;
        float v0 = pval[base], v1 = pval[base + 1], v2 = pval[base + 2];
        int i0 = pidx[base], i1 = pidx[base + 1], i2 = pidx[base + 2];
        #pragma unroll
        for (int r = 0; r < NCAND; ++r) {
            float av = v0; int ai = i0;
            amin(av, ai, v1, i1);
            amin(av, ai, v2, i2);
            #pragma unroll
            for (int m = 1; m < 64; m <<= 1) {
                float ov = __shfl_xor(av, m);
                int oi = __shfl_xor(ai, m);
                amin(av, ai, ov, oi);
            }
            if (ai == i0) v0 = FINF;   // consume (indices unique across partials)
            if (ai == i1) v1 = FINF;
            if (ai == i2) v2 = FINF;
            if (t == 0) scand[r] = ai;
        }
    }
    __syncthreads();

    // --- exact fp32 rescore: wave w handles candidates w and w+4
    const int wv = t >> 6;
    const int l = t & 63;
    const float4* r4row = reinterpret_cast<const float4*>(resid + (size_t)b * D_);
    float4 rx[4];
    #pragma unroll
    for (int q = 0; q < 4; ++q) rx[q] = r4row[q * 64 + l];

    #pragma unroll
    for (int cpass = 0; cpass < 2; ++cpass) {
        const int c = wv + cpass * 4;
        const int idx = scand[c];
        const float4* e4 = reinterpret_cast<const float4*>(E + (size_t)idx * D_);
        float dot = 0.f;
        #pragma unroll
        for (int q = 0; q < 4; ++q) {
            float4 e = e4[q * 64 + l];
            dot = fmaf(rx[q].x, e.x, dot);
            dot = fmaf(rx[q].y, e.y, dot);
            dot = fmaf(rx[q].z, e.z, dot);
            dot = fmaf(rx[q].w, e.w, dot);
        }
        #pragma unroll
        for (int m = 1; m < 64; m <<= 1) dot += __shfl_xor(dot, m);
        if (l == 0) sdot[c] = dot;
    }
    __syncthreads();

    if (t == 0) {
        const float rv = rr[b];
        float bv = FINF; int bi = IBIG;
        #pragma unroll
        for (int c = 0; c < NCAND; ++c) {
            const int idx = scand[c];
            const float s = (rv - 2.0f * sdot[c]) + ee[idx];
            amin(bv, bi, s, idx);
        }
        ssel = bi;
        codes[(size_t)b * H_ + h] = (float)bi;
    }
    __syncthreads();
    const int idx = ssel;

    // --- exact fp32 update (order matches reference elementwise)
    const float4* q4 = reinterpret_cast<const float4*>(E + (size_t)idx * D_);
    float4* r4 = reinterpret_cast<float4*>(resid + (size_t)b * D_);
    float4* o4 = reinterpret_cast<float4*>(quant + (size_t)b * D_);

    float4 q = q4[t];
    float4 r = r4[t];
    r.x -= q.x; r.y -= q.y; r.z -= q.z; r.w -= q.w;
    r4[t] = r;

    ushort4 hh;
    hh.x = f2bf_rn(r.x); hh.y = f2bf_rn(r.y);
    hh.z = f2bf_rn(r.z); hh.w = f2bf_rn(r.w);
    reinterpret_cast<ushort4*>(rhi + (size_t)b * D_)[t] = hh;

    float4 o;
    if (h == 0) {
        o = q;
    } else {
        o = o4[t];
        o.x += q.x; o.y += q.y; o.z += q.z; o.w += q.w;
    }
    o4[t] = o;

    float s = r.x * r.x + r.y * r.y + r.z * r.z + r.w * r.w;
    #pragma unroll
    for (int m = 1; m < 64; m <<= 1) s += __shfl_xor(s, m);
    if ((t & 63) == 0) ls[t >> 6] = s;
    __syncthreads();
    if (t == 0) rr[b] = (ls[0] + ls[1]) + (ls[2] + ls[3]);
}

// ---------------------------------------------------------------------------
extern "C" void kernel_launch(void* const* d_in, const int* in_sizes, int n_in,
                              void* d_out, int out_size, void* d_ws, size_t ws_size,
                              hipStream_t stream) {
    const float* x  = (const float*)d_in[0];   // [B][1][D]
    const float* cb = (const float*)d_in[1];   // [H][K][D]
    float* out = (float*)d_out;
    float* quant = out;                          // [B][D]
    float* codes = out + (size_t)B_ * D_;        // [B][H] as float

    char* ws = (char*)d_ws;
    size_t off = 0;
    float* resid = (float*)(ws + off); off += (size_t)B_ * D_ * 4;             // 32 MB
    float* rr    = (float*)(ws + off); off += (size_t)B_ * 4;
    float* ee    = (float*)(ws + off); off += (size_t)H_ * K_ * 4;             // 128 KB
    float* pval  = (float*)(ws + off); off += (size_t)B_ * NBLK * TOPB * 4;    // 6.3 MB
    int*   pidx  = (int*)  (ws + off); off += (size_t)B_ * NBLK * TOPB * 4;    // 6.3 MB
    unsigned short* rhi = (unsigned short*)(ws + off); off += (size_t)B_ * D_ * 2;  // 16 MB
    unsigned short* chi = (unsigned short*)(ws + off); off += (size_t)K_ * D_ * 2;  // 8 MB

    hipLaunchKernelGGL(init_kernel, dim3(B_), dim3(256), 0, stream, x, resid, rr, rhi);

    for (int h = 0; h < H_; ++h) {
        const float* E  = cb + (size_t)h * K_ * D_;
        float* eh = ee + (size_t)h * K_;
        hipLaunchKernelGGL(cbconv_kernel, dim3(K_), dim3(256), 0, stream, E, chi, eh);
        hipLaunchKernelGGL(score_mfma_kernel, dim3(K_ / BN, B_ / BM), dim3(256), 0, stream,
                           rhi, chi, eh, rr, pval, pidx);
        hipLaunchKernelGGL(update_kernel, dim3(B_), dim3(256), 0, stream,
                           resid, E, eh, pval, pidx, rr, quant, codes, rhi, h);
    }
}